// Round 16
// baseline (156.868 us; speedup 1.0000x reference)
//
#include <hip/hip_runtime.h>

// GCN 2-layer forward, fp32 in/out, fp16 gather tables. Build: 1-pass
// fixed-capacity bucket partition + per-bucket sort -> PADDED CSR (pad to
// mult of 16, pads -> row n of zeroed table; zero-degree pse=(0,0)).
// Bucket b owns packed[b*CAPB,(b+1)*CAPB); clamped writes; gcursor[b]-
// b*CAPB = bucket count -> no count/scan passes (r14: -20.6us).
// Aggregates: one wave per TWO nodes, 4B/lane gathers, int4/int2 broadcast
// srcs, 2-deep rotation, per-node fmaf masks. Segment-minimal (1/edge).
// Mechanism ledger: time = VMEM SEGMENTS x ~4.9cy (TA issue) when L2-hit,
// + miss path; traffic irrelevant (r18); depth>2 regresses (r17);
// residency splits regress (r10/r17/r18); wide gathers -2.7us (r12);
// sort 1024thr -4.2us (r13); drop count/scan -20.6us (r14).
// r27 (resubmit after infra failure): dense1 was segment-bound too (38.4us
// measured r14: 8-lane broadcast float4 x-loads = 16 segs/wave-iter ~=
// 25us TA). Stage x-tile in LDS with COALESCED loads (Xs[64][132], 33.8KB;
// +Wt 16.9KB = 50.7KB, 3 blocks/CU), compute from LDS (conflict-free).
// Layer-2 dense unchanged (segment cost ~4us, not worth LDS).

#define WAVE 64
#define BN2 512           // nodes per bucket (9 bits local col)
#define BN2_SH 9
#define NBMAX 256         // max coarse buckets (N <= 131072)
#define CHUNK 8192        // edges per partition block
#define CAPB 32768        // packed capacity per bucket (2x uniform mean)

typedef _Float16 f16;
typedef f16 f16x2 __attribute__((ext_vector_type(2)));

// ---- init: gcursor ramp (b*CAPB), gpcur=0, zero dummy table rows ----
__global__ void init_kernel(int* __restrict__ gcur, int* __restrict__ gpcur,
                            f16* __restrict__ hA, f16* __restrict__ h2t,
                            int nzr, int nb) {
    int lane = threadIdx.x;  // single wave
    if (lane == 0) gpcur[0] = 0;
    if (lane < 32)      hA[(size_t)nzr * 32 + lane]         = (f16)0.f;
    else if (lane < 48) h2t[(size_t)nzr * 16 + (lane - 32)] = (f16)0.f;
    for (int b = lane; b < nb; b += WAVE) gcur[b] = b * CAPB;
}

// ---- pass 1: LDS-binned partition of packed (src<<BN2_SH | local_col)
//      into fixed-capacity bucket regions (clamped on overflow). ----
__global__ void __launch_bounds__(512)
partition_kernel(const int* __restrict__ row, const int* __restrict__ col,
                 int* __restrict__ gcursor, unsigned* __restrict__ packed,
                 int E, int nb) {
    __shared__ int hist[NBMAX], excl[NBMAX], cursor[NBMAX], baseoff[NBMAX];
    __shared__ unsigned stage[CHUNK];
    int chunk0 = blockIdx.x * CHUNK;
    int cn = E - chunk0; if (cn > CHUNK) cn = CHUNK;
    for (int i = threadIdx.x; i < nb; i += blockDim.x) hist[i] = 0;
    __syncthreads();
    for (int i = threadIdx.x; i < cn; i += blockDim.x)
        atomicAdd(&hist[col[chunk0 + i] >> BN2_SH], 1);
    __syncthreads();
    if (threadIdx.x < WAVE) {
        int lane = threadIdx.x, carry = 0;
        for (int base = 0; base < nb; base += WAVE) {
            int i = base + lane;
            int orig = (i < nb) ? hist[i] : 0;
            int v = orig;
#pragma unroll
            for (int off = 1; off < WAVE; off <<= 1) {
                int t = __shfl_up(v, off, WAVE);
                if (lane >= off) v += t;
            }
            if (i < nb) { excl[i] = carry + v - orig; cursor[i] = carry + v - orig; }
            carry += __shfl(v, WAVE - 1, WAVE);
        }
    }
    __syncthreads();
    for (int b = threadIdx.x; b < nb; b += blockDim.x) {
        int c = hist[b];
        baseoff[b] = c ? atomicAdd(&gcursor[b], c) : 0;
    }
    __syncthreads();
    for (int i = threadIdx.x; i < cn; i += blockDim.x) {
        int c = col[chunk0 + i], r = row[chunk0 + i];
        int b = c >> BN2_SH;
        int pos = atomicAdd(&cursor[b], 1);
        stage[pos] = ((unsigned)r << BN2_SH) | (unsigned)(c & (BN2 - 1));
    }
    __syncthreads();
    int wave = threadIdx.x >> 6, lane = threadIdx.x & 63, nw = blockDim.x >> 6;
    for (int b = wave; b < nb; b += nw) {
        int c = hist[b]; if (!c) continue;
        int s = excl[b], d = baseoff[b];
        int lim = (b + 1) * CAPB;   // clamp: never cross into next region
        for (int k = lane; k < c; k += WAVE)
            if (d + k < lim) packed[d + k] = stage[s + k];
    }
}

// ---- pass 2: per-bucket sort by local node -> padded srcs, pse, dinv. ----
__global__ void __launch_bounds__(1024)
sort_kernel(const int* __restrict__ gcursor, const unsigned* __restrict__ packed,
            int* __restrict__ srcs, int2* __restrict__ pse,
            float* __restrict__ dinv, int* __restrict__ gpcur,
            int n, int nb, int E) {
    __shared__ int hist[BN2], pex[BN2], cur[BN2];
    __shared__ int pbase_s;
    int b = blockIdx.x;
    int start = b * CAPB;
    int end = gcursor[b];
    int lim = start + CAPB;
    if (end > lim) end = lim;
    for (int i = threadIdx.x; i < BN2; i += blockDim.x) { hist[i] = 0; cur[i] = 0; }
    __syncthreads();
    for (int k = start + threadIdx.x; k < end; k += blockDim.x)
        atomicAdd(&hist[packed[k] & (BN2 - 1)], 1);
    __syncthreads();
    if (threadIdx.x < WAVE) {   // scan of PADDED degrees over BN2 locals
        int lane = threadIdx.x, carry = 0;
#pragma unroll
        for (int base = 0; base < BN2; base += WAVE) {
            int i = base + lane;
            int pd = (hist[i] + 15) & ~15;
            int v = pd;
#pragma unroll
            for (int off = 1; off < WAVE; off <<= 1) {
                int t = __shfl_up(v, off, WAVE);
                if (lane >= off) v += t;
            }
            pex[i] = carry + v - pd;
            carry += __shfl(v, WAVE - 1, WAVE);
        }
        if (lane == 0) pbase_s = atomicAdd(gpcur, carry);
    }
    __syncthreads();
    int pbase = pbase_s;
    for (int i = threadIdx.x; i < BN2; i += blockDim.x) {
        int node = b * BN2 + i;
        if (node < n) {
            int d = hist[i], pd = (d + 15) & ~15;
            int ps = pbase + pex[i];
            pse[node]  = d ? make_int2(ps, ps + pd) : make_int2(0, 0);
            dinv[node] = d ? rsqrtf((float)d) : 0.f;
            for (int k = d; k < pd; ++k) srcs[ps + k] = n;   // dummy zero-row
        }
    }
    __syncthreads();
    for (int k = start + threadIdx.x; k < end; k += blockDim.x) {
        unsigned p = packed[k];
        int lc = p & (BN2 - 1);
        int pos = atomicAdd(&cur[lc], 1);
        srcs[pbase + pex[lc] + pos] = (int)(p >> BN2_SH);
    }
}

// ---- dense layer 1 (INC=128, OUTC=32): LDS-staged x-tile (coalesced
//      global reads), thread = 2 nodes x 4 j (JT=8). Xs/Wt stride 132 ->
//      conflict-free (bank group = 4*sp / 4*jg). 64 nodes/block. ----
__global__ void __launch_bounds__(256)
dense1_kernel(const float* __restrict__ x, const float* __restrict__ W,
              const float* __restrict__ dinv, f16* __restrict__ h, int n) {
    const int INC = 128, OUTC = 32, JT = 8;
    const int LSTR = INC + 4;      // 132
    const int XSTR = INC + 4;      // 132
    __shared__ float Wt[OUTC * LSTR];    // 16.9 KB
    __shared__ float Xs[64 * XSTR];      // 33.8 KB
    int base = blockIdx.x * 64;
    for (int i = threadIdx.x; i < INC * OUTC; i += 256) {
        int k = i / OUTC, j = i % OUTC;
        Wt[j * LSTR + k] = W[i];
    }
    // stage 64 rows coalesced: 32 consecutive lanes cover one 512B row
    for (int i = threadIdx.x; i < 64 * 32; i += 256) {
        int r = i >> 5, c = i & 31;
        int nn = base + r;
        int nc = nn < n ? nn : n - 1;
        float4 v = *(const float4*)(x + (size_t)nc * INC + 4 * c);
        *(float4*)(Xs + r * XSTR + 4 * c) = v;
    }
    __syncthreads();
    const int jg = threadIdx.x % JT;   // 0..7
    const int sp = threadIdx.x / JT;   // 0..31
    int n0 = base + sp;
    int n1 = base + sp + 32;
    const float* xr0 = Xs + sp * XSTR;
    const float* xr1 = Xs + (sp + 32) * XSTR;
    float a[2][4] = {{0.f, 0.f, 0.f, 0.f}, {0.f, 0.f, 0.f, 0.f}};
#pragma unroll 4
    for (int k4 = 0; k4 < INC / 4; ++k4) {
        float4 v0 = *(const float4*)(xr0 + 4 * k4);
        float4 v1 = *(const float4*)(xr1 + 4 * k4);
#pragma unroll
        for (int u = 0; u < 4; ++u) {
            float4 w = *(const float4*)(Wt + (jg + u * JT) * LSTR + 4 * k4);
            a[0][u] = fmaf(v0.x, w.x, fmaf(v0.y, w.y, fmaf(v0.z, w.z, fmaf(v0.w, w.w, a[0][u]))));
            a[1][u] = fmaf(v1.x, w.x, fmaf(v1.y, w.y, fmaf(v1.z, w.z, fmaf(v1.w, w.w, a[1][u]))));
        }
    }
#pragma unroll
    for (int pair = 0; pair < 2; ++pair) {
        int nn = pair ? n1 : n0;
        if (nn < n) {
            float d = dinv[nn];
            f16* hr = h + (size_t)nn * OUTC;
#pragma unroll
            for (int u = 0; u < 4; ++u) hr[jg + u * JT] = (f16)(a[pair][u] * d);
        }
    }
}

// ---- dense generic (layer 2): thread = 2 nodes x 4 j. W^T in LDS. ----
template <int INC, int OUTC, int JT>
__global__ void __launch_bounds__(256, 4)
dense_kernel(const float* __restrict__ x, const float* __restrict__ W,
             const float* __restrict__ dinv, f16* __restrict__ h, int n) {
    const int LSTR = INC + 4;
    const int SP   = 256 / JT;     // node slots (pairs) per block
    const int NT   = SP * 2;       // nodes per block
    __shared__ float Wt[OUTC * LSTR];
    for (int i = threadIdx.x; i < INC * OUTC; i += 256) {
        int k = i / OUTC, j = i % OUTC;
        Wt[j * LSTR + k] = W[i];
    }
    __syncthreads();
    const int jg = threadIdx.x % JT;
    const int sp = threadIdx.x / JT;
    int base = blockIdx.x * NT;
    int n0 = base + sp;
    int n1 = base + sp + SP;
    int n0c = n0 < n ? n0 : n - 1;   // clamp reads, guard writes
    int n1c = n1 < n ? n1 : n - 1;
    const float4* xr0 = (const float4*)(x + (size_t)n0c * INC);
    const float4* xr1 = (const float4*)(x + (size_t)n1c * INC);
    float a[2][4] = {{0.f, 0.f, 0.f, 0.f}, {0.f, 0.f, 0.f, 0.f}};
#pragma unroll 4
    for (int k4 = 0; k4 < INC / 4; ++k4) {
        float4 v0 = xr0[k4];
        float4 v1 = xr1[k4];
#pragma unroll
        for (int u = 0; u < 4; ++u) {
            float4 w = *(const float4*)(Wt + (jg + u * JT) * LSTR + 4 * k4);
            a[0][u] = fmaf(v0.x, w.x, fmaf(v0.y, w.y, fmaf(v0.z, w.z, fmaf(v0.w, w.w, a[0][u]))));
            a[1][u] = fmaf(v1.x, w.x, fmaf(v1.y, w.y, fmaf(v1.z, w.z, fmaf(v1.w, w.w, a[1][u]))));
        }
    }
#pragma unroll
    for (int pair = 0; pair < 2; ++pair) {
        int nn = pair ? n1 : n0;
        if (nn < n) {
            float d = dinv[nn];
            f16* hr = h + (size_t)nn * OUTC;
#pragma unroll
            for (int u = 0; u < 4; ++u) hr[jg + u * JT] = (f16)(a[pair][u] * d);
        }
    }
}

// ---- layer-1 aggregate: one wave per TWO nodes; 4B/lane (2 cols), 16
//      lanes per 64B row, eo=lane>>4 -> 4 rows per gather inst. Per node
//      per 16-edge step: 1 int4 srcs (broadcast) + 4 gathers. 2-deep
//      rotation, per-node fmaf masks. Output: float2 per lane. ----
#define GLD32I(s) (*(const int*)(hb + (((unsigned)(s) << 6) + j4)))

template <bool RELU>
__global__ void __launch_bounds__(256)
csr_agg32w_kernel(const int2* __restrict__ pse, const int* __restrict__ srcs,
                  const float* __restrict__ dinv, const f16* __restrict__ hs,
                  const float* __restrict__ bias, float* __restrict__ out,
                  int ostride, int n) {
    int lane = threadIdx.x & 63;
    int wid  = threadIdx.x >> 6;
    int j  = lane & 15;           // col pair (2j, 2j+1)
    int eo = lane >> 4;           // 0..3 row slot
    int n0 = ((int)blockIdx.x * 4 + wid) * 2;
    if (n0 >= n) return;
    int n1 = n0 + 1;
    bool v1 = n1 < n;
    int4 se = *(const int4*)(pse + n0);      // pse[n0], pse[n1]
    int nb0 = (se.y - se.x) >> 4;            // 16-edge blocks
    int nb1 = v1 ? ((se.w - se.z) >> 4) : 0;
    float dv0 = dinv[n0];
    float dv1 = v1 ? dinv[n1] : 0.f;
    float2 bj = ((const float2*)bias)[j];
    float2* op0 = (float2*)(out + (size_t)n0 * ostride) + j;
    float2* op1 = (float2*)(out + (size_t)n1 * ostride) + j;
    int MAXB = nb0 > nb1 ? nb0 : nb1;
    if (MAXB == 0) {
        float2 v = bj;
        if (RELU) { v.x = v.x > 0.f ? v.x : 0.f; v.y = v.y > 0.f ? v.y : 0.f; }
        if (eo == 0) *op0 = v;
        else if (eo == 1 && v1) *op1 = v;
        return;
    }
    const unsigned j4 = (unsigned)(j << 2);
    const char* hb = (const char*)hs;
    const int4* P0 = (const int4*)(srcs + se.x) + eo;
    const int4* P1 = (const int4*)(srcs + (v1 ? se.z : se.x)) + eo;
    int nc0 = nb0 > 1 ? nb0 : 1;
    int nc1 = nb1 > 1 ? nb1 : 1;
    int4 sA0 = P0[0];
    int4 sA1 = P1[0];
    int a0 = GLD32I(sA0.x), a1 = GLD32I(sA0.y), a2 = GLD32I(sA0.z), a3 = GLD32I(sA0.w);
    int a4 = GLD32I(sA1.x), a5 = GLD32I(sA1.y), a6 = GLD32I(sA1.z), a7 = GLD32I(sA1.w);
    int4 sB0 = P0[(nc0 > 1 ? 1 : 0) * 4];
    int4 sB1 = P1[(nc1 > 1 ? 1 : 0) * 4];
    float aL0 = 0.f, aH0 = 0.f, aL1 = 0.f, aH1 = 0.f;
    for (int b = 0; b < MAXB - 1; ++b) {
        // gathers for block b+1
        int g0 = GLD32I(sB0.x), g1 = GLD32I(sB0.y), g2 = GLD32I(sB0.z), g3 = GLD32I(sB0.w);
        int g4 = GLD32I(sB1.x), g5 = GLD32I(sB1.y), g6 = GLD32I(sB1.z), g7 = GLD32I(sB1.w);
        // srcs for block b+2 (clamped per node)
        int x0 = (b + 2) < nc0 ? (b + 2) : nc0 - 1;
        int x1 = (b + 2) < nc1 ? (b + 2) : nc1 - 1;
        int4 t0 = P0[x0 * 4];
        int4 t1 = P1[x1 * 4];
        // consume block b (masked per node)
        float m0 = b < nb0 ? 1.f : 0.f;
        float m1 = b < nb1 ? 1.f : 0.f;
        f16x2 p;
        p = __builtin_bit_cast(f16x2, a0); aL0 = fmaf(m0, (float)p.x, aL0); aH0 = fmaf(m0, (float)p.y, aH0);
        p = __builtin_bit_cast(f16x2, a1); aL0 = fmaf(m0, (float)p.x, aL0); aH0 = fmaf(m0, (float)p.y, aH0);
        p = __builtin_bit_cast(f16x2, a2); aL0 = fmaf(m0, (float)p.x, aL0); aH0 = fmaf(m0, (float)p.y, aH0);
        p = __builtin_bit_cast(f16x2, a3); aL0 = fmaf(m0, (float)p.x, aL0); aH0 = fmaf(m0, (float)p.y, aH0);
        p = __builtin_bit_cast(f16x2, a4); aL1 = fmaf(m1, (float)p.x, aL1); aH1 = fmaf(m1, (float)p.y, aH1);
        p = __builtin_bit_cast(f16x2, a5); aL1 = fmaf(m1, (float)p.x, aL1); aH1 = fmaf(m1, (float)p.y, aH1);
        p = __builtin_bit_cast(f16x2, a6); aL1 = fmaf(m1, (float)p.x, aL1); aH1 = fmaf(m1, (float)p.y, aH1);
        p = __builtin_bit_cast(f16x2, a7); aL1 = fmaf(m1, (float)p.x, aL1); aH1 = fmaf(m1, (float)p.y, aH1);
        a0 = g0; a1 = g1; a2 = g2; a3 = g3;
        a4 = g4; a5 = g5; a6 = g6; a7 = g7;
        sB0 = t0; sB1 = t1;
    }
    {   // epilogue: block MAXB-1
        float m0 = (MAXB - 1) < nb0 ? 1.f : 0.f;
        float m1 = (MAXB - 1) < nb1 ? 1.f : 0.f;
        f16x2 p;
        p = __builtin_bit_cast(f16x2, a0); aL0 = fmaf(m0, (float)p.x, aL0); aH0 = fmaf(m0, (float)p.y, aH0);
        p = __builtin_bit_cast(f16x2, a1); aL0 = fmaf(m0, (float)p.x, aL0); aH0 = fmaf(m0, (float)p.y, aH0);
        p = __builtin_bit_cast(f16x2, a2); aL0 = fmaf(m0, (float)p.x, aL0); aH0 = fmaf(m0, (float)p.y, aH0);
        p = __builtin_bit_cast(f16x2, a3); aL0 = fmaf(m0, (float)p.x, aL0); aH0 = fmaf(m0, (float)p.y, aH0);
        p = __builtin_bit_cast(f16x2, a4); aL1 = fmaf(m1, (float)p.x, aL1); aH1 = fmaf(m1, (float)p.y, aH1);
        p = __builtin_bit_cast(f16x2, a5); aL1 = fmaf(m1, (float)p.x, aL1); aH1 = fmaf(m1, (float)p.y, aH1);
        p = __builtin_bit_cast(f16x2, a6); aL1 = fmaf(m1, (float)p.x, aL1); aH1 = fmaf(m1, (float)p.y, aH1);
        p = __builtin_bit_cast(f16x2, a7); aL1 = fmaf(m1, (float)p.x, aL1); aH1 = fmaf(m1, (float)p.y, aH1);
    }
    // reduce over the 4 eo groups
    aL0 += __shfl_xor(aL0, 16, WAVE); aL0 += __shfl_xor(aL0, 32, WAVE);
    aH0 += __shfl_xor(aH0, 16, WAVE); aH0 += __shfl_xor(aH0, 32, WAVE);
    aL1 += __shfl_xor(aL1, 16, WAVE); aL1 += __shfl_xor(aL1, 32, WAVE);
    aH1 += __shfl_xor(aH1, 16, WAVE); aH1 += __shfl_xor(aH1, 32, WAVE);
    if (eo == 0) {
        float2 v = make_float2(fmaf(aL0, dv0, bj.x), fmaf(aH0, dv0, bj.y));
        if (RELU) { v.x = v.x > 0.f ? v.x : 0.f; v.y = v.y > 0.f ? v.y : 0.f; }
        *op0 = v;
    } else if (eo == 1 && v1) {
        float2 v = make_float2(fmaf(aL1, dv1, bj.x), fmaf(aH1, dv1, bj.y));
        if (RELU) { v.x = v.x > 0.f ? v.x : 0.f; v.y = v.y > 0.f ? v.y : 0.f; }
        *op1 = v;
    }
}

// ---- layer-2 aggregate: 4B/lane, 8 lanes per 32B row, eo=lane>>3 -> 8
//      rows per gather inst. 2-deep rotation, per-node masks. ----
#define GLD16I(s) (*(const int*)(hb + (((unsigned)(s) << 5) + j4)))

template <bool RELU>
__global__ void __launch_bounds__(256)
csr_agg16w_kernel(const int2* __restrict__ pse, const int* __restrict__ srcs,
                  const float* __restrict__ dinv, const f16* __restrict__ hs,
                  const float* __restrict__ bias, float* __restrict__ out,
                  int ostride, int n, int tailidx) {
    int bid = blockIdx.x;
    int lane = threadIdx.x & 63;
    int wid  = threadIdx.x >> 6;
    int j  = lane & 7;            // col pair (2j, 2j+1)
    int eo = lane >> 3;           // 0..7 row slot
    if (tailidx >= 0 && bid == 0 && threadIdx.x == 0) out[tailidx] = 0.f;
    int n0 = (bid * 4 + wid) * 2;
    if (n0 >= n) return;
    int n1 = n0 + 1;
    bool v1 = n1 < n;
    int4 se = *(const int4*)(pse + n0);      // pse[n0], pse[n1]
    int nb0 = (se.y - se.x) >> 4;            // 16-edge blocks
    int nb1 = v1 ? ((se.w - se.z) >> 4) : 0;
    float dv0 = dinv[n0];
    float dv1 = v1 ? dinv[n1] : 0.f;
    float2 bj = ((const float2*)bias)[j];
    float2* op0 = (float2*)(out + (size_t)n0 * ostride) + j;
    float2* op1 = (float2*)(out + (size_t)n1 * ostride) + j;
    int MAXB = nb0 > nb1 ? nb0 : nb1;
    if (MAXB == 0) {
        float2 v = bj;
        if (RELU) { v.x = v.x > 0.f ? v.x : 0.f; v.y = v.y > 0.f ? v.y : 0.f; }
        if (eo == 0) *op0 = v;
        else if (eo == 1 && v1) *op1 = v;
        return;
    }
    const unsigned j4 = (unsigned)(j << 2);
    const char* hb = (const char*)hs;
    const int2* P0 = (const int2*)(srcs + se.x) + eo;
    const int2* P1 = (const int2*)(srcs + (v1 ? se.z : se.x)) + eo;
    int nc0 = nb0 > 1 ? nb0 : 1;
    int nc1 = nb1 > 1 ? nb1 : 1;
    int2 sA0 = P0[0];
    int2 sA1 = P1[0];
    int a0 = GLD16I(sA0.x), a1 = GLD16I(sA0.y);
    int a2 = GLD16I(sA1.x), a3 = GLD16I(sA1.y);
    int2 sB0 = P0[(nc0 > 1 ? 1 : 0) * 8];
    int2 sB1 = P1[(nc1 > 1 ? 1 : 0) * 8];
    float aL0 = 0.f, aH0 = 0.f, aL1 = 0.f, aH1 = 0.f;
    for (int b = 0; b < MAXB - 1; ++b) {
        int g0 = GLD16I(sB0.x), g1 = GLD16I(sB0.y);
        int g2 = GLD16I(sB1.x), g3 = GLD16I(sB1.y);
        int x0 = (b + 2) < nc0 ? (b + 2) : nc0 - 1;
        int x1 = (b + 2) < nc1 ? (b + 2) : nc1 - 1;
        int2 t0 = P0[x0 * 8];
        int2 t1 = P1[x1 * 8];
        float m0 = b < nb0 ? 1.f : 0.f;
        float m1 = b < nb1 ? 1.f : 0.f;
        f16x2 p;
        p = __builtin_bit_cast(f16x2, a0); aL0 = fmaf(m0, (float)p.x, aL0); aH0 = fmaf(m0, (float)p.y, aH0);
        p = __builtin_bit_cast(f16x2, a1); aL0 = fmaf(m0, (float)p.x, aL0); aH0 = fmaf(m0, (float)p.y, aH0);
        p = __builtin_bit_cast(f16x2, a2); aL1 = fmaf(m1, (float)p.x, aL1); aH1 = fmaf(m1, (float)p.y, aH1);
        p = __builtin_bit_cast(f16x2, a3); aL1 = fmaf(m1, (float)p.x, aL1); aH1 = fmaf(m1, (float)p.y, aH1);
        a0 = g0; a1 = g1; a2 = g2; a3 = g3;
        sB0 = t0; sB1 = t1;
    }
    {   // epilogue: block MAXB-1
        float m0 = (MAXB - 1) < nb0 ? 1.f : 0.f;
        float m1 = (MAXB - 1) < nb1 ? 1.f : 0.f;
        f16x2 p;
        p = __builtin_bit_cast(f16x2, a0); aL0 = fmaf(m0, (float)p.x, aL0); aH0 = fmaf(m0, (float)p.y, aH0);
        p = __builtin_bit_cast(f16x2, a1); aL0 = fmaf(m0, (float)p.x, aL0); aH0 = fmaf(m0, (float)p.y, aH0);
        p = __builtin_bit_cast(f16x2, a2); aL1 = fmaf(m1, (float)p.x, aL1); aH1 = fmaf(m1, (float)p.y, aH1);
        p = __builtin_bit_cast(f16x2, a3); aL1 = fmaf(m1, (float)p.x, aL1); aH1 = fmaf(m1, (float)p.y, aH1);
    }
    // reduce over the 8 eo groups
    aL0 += __shfl_xor(aL0, 8, WAVE); aL0 += __shfl_xor(aL0, 16, WAVE); aL0 += __shfl_xor(aL0, 32, WAVE);
    aH0 += __shfl_xor(aH0, 8, WAVE); aH0 += __shfl_xor(aH0, 16, WAVE); aH0 += __shfl_xor(aH0, 32, WAVE);
    aL1 += __shfl_xor(aL1, 8, WAVE); aL1 += __shfl_xor(aL1, 16, WAVE); aL1 += __shfl_xor(aL1, 32, WAVE);
    aH1 += __shfl_xor(aH1, 8, WAVE); aH1 += __shfl_xor(aH1, 16, WAVE); aH1 += __shfl_xor(aH1, 32, WAVE);
    if (eo == 0) {
        float2 v = make_float2(fmaf(aL0, dv0, bj.x), fmaf(aH0, dv0, bj.y));
        if (RELU) { v.x = v.x > 0.f ? v.x : 0.f; v.y = v.y > 0.f ? v.y : 0.f; }
        *op0 = v;
    } else if (eo == 1 && v1) {
        float2 v = make_float2(fmaf(aL1, dv1, bj.x), fmaf(aH1, dv1, bj.y));
        if (RELU) { v.x = v.x > 0.f ? v.x : 0.f; v.y = v.y > 0.f ? v.y : 0.f; }
        *op1 = v;
    }
}

extern "C" void kernel_launch(void* const* d_in, const int* in_sizes, int n_in,
                              void* d_out, int out_size, void* d_ws, size_t ws_size,
                              hipStream_t stream) {
    const float* x  = (const float*)d_in[0];
    const int*   ei = (const int*)d_in[1];    // harness converts int64 -> int32
    const float* W1 = (const float*)d_in[2];
    const float* b1 = (const float*)d_in[3];
    const float* W2 = (const float*)d_in[4];
    const float* b2 = (const float*)d_in[5];

    const int IN_C = 128, HID = 32, OC = 16;
    const int N = in_sizes[0] / IN_C;       // 100000
    const int E = in_sizes[1] / 2;          // 3200000
    const int* row = ei;
    const int* col = ei + E;
    const int NB = (N + BN2 - 1) / BN2;     // 196 coarse buckets

    char* base = (char*)d_ws;
    size_t off = 0;
    auto carve = [&](size_t bytes) -> char* {
        char* p = base + off;
        off = (off + bytes + 255) & ~(size_t)255;
        return p;
    };
    int*      gcur  = (int*)     carve((size_t)NB * 4);
    int*      gpcur = (int*)     carve(8);
    float*    dinv  = (float*)   carve((size_t)N * 4);
    int2*     pse   = (int2*)    carve((size_t)(N + 2) * 8);
    unsigned* packed= (unsigned*)carve((size_t)NB * CAPB * 4);   // fixed-cap regions
    int*      srcsP = (int*)     carve(((size_t)E + (size_t)N * 32 + 256) * 4); // pads + slack
    f16*      hA    = (f16*)     carve((size_t)(N + 1) * 32 * 2);  // layer1 table, 64B rows (+zero row)
    f16*      h2t   = (f16*)     carve((size_t)(N + 1) * 16 * 2);  // layer2 table (+zero row)
    float*    bufB  = (float*)   carve((size_t)N * HID * 4);       // relu(agg1), fp32
    (void)ws_size; (void)n_in;

    float* outp = (float*)d_out;

    // build: init + 1-pass fixed-capacity partition + per-bucket sort
    init_kernel<<<1, 64, 0, stream>>>(gcur, gpcur, hA, h2t, N, NB);
    partition_kernel<<<(E + CHUNK - 1) / CHUNK, 512, 0, stream>>>(row, col, gcur, packed, E, NB);
    sort_kernel<<<NB, 1024, 0, stream>>>(gcur, packed, srcsP, pse, dinv, gpcur, N, NB, E);

    int npb = 8;                         // 4 waves x 2 nodes per block
    int g2  = (N + npb - 1) / npb;       // 12500 blocks

    // layer 1: hA = fp16((x@W1)*dinv) ; bufB = relu(dinv*agg(hA) + b1)
    {
        dense1_kernel<<<(N + 63) / 64, 256, 0, stream>>>(x, W1, dinv, hA, N);
        csr_agg32w_kernel<true><<<g2, 256, 0, stream>>>(
            pse, srcsP, dinv, hA, b1, bufB, HID, N);
    }
    // layer 2: h2t = fp16((bufB@W2)*dinv) ; out = dinv*agg(h2t) + b2
    {
        const int NT = (256 / 4) * 2;  // 128 nodes per block
        dense_kernel<32, 16, 4><<<(N + NT - 1) / NT, 256, 0, stream>>>(bufB, W2, dinv, h2t, N);
        int tailidx = (out_size > N * OC) ? (N * OC) : -1;
        csr_agg16w_kernel<false><<<g2, 256, 0, stream>>>(
            pse, srcsP, dinv, h2t, b2, outp, OC, N, tailidx);
    }
}